// Round 1
// baseline (29.472 us; speedup 1.0000x reference)
//
#include <hip/hip_runtime.h>
#include <math.h>

namespace {
constexpr int B = 8, H = 192, W = 192;
constexpr float BIGF = 73728.0f; // H*H + W*W
}

// Pass 1: vertical L1 distance to nearest fg in the same column, squared.
// One thread per (b, j) column. Writes g2 into `buf` (which is d_out).
__global__ void dm_vert(const float* __restrict__ mask, float* __restrict__ buf) {
    int tid = blockIdx.x * blockDim.x + threadIdx.x;
    if (tid >= B * W) return;
    int b = tid / W;
    int j = tid - b * W;
    const float* mcol = mask + (size_t)b * H * W + j;
    float* gcol = buf + (size_t)b * H * W + j;

    // downward scan: distance to nearest fg at-or-above (cummax semantics:
    // fg at i itself gives 0). No fg yet -> last = -BIG -> up = i + BIG.
    float last = -BIGF;
    #pragma unroll 8
    for (int i = 0; i < H; ++i) {
        float m = mcol[(size_t)i * W];
        float fi = (float)i;
        if (m > 0.5f) last = fi;
        gcol[(size_t)i * W] = fi - last; // store "up"
    }
    // upward scan: nearest fg at-or-below; none -> nxt = BIG -> down = BIG - i
    // (matches reference's flipped-cummax algebra exactly).
    float nxt = BIGF;
    #pragma unroll 8
    for (int i = H - 1; i >= 0; --i) {
        float m = mcol[(size_t)i * W];
        float fi = (float)i;
        if (m > 0.5f) nxt = fi;
        float up = gcol[(size_t)i * W];
        float d = fminf(fminf(up, nxt - fi), BIGF);
        gcol[(size_t)i * W] = d * d; // store squared vertical distance
    }
}

// Pass 2: exact 1D EDT along rows (brute force, identical to reference),
// fused with sqrt/scale/sigmoid epilogue. One block per (b, i) row.
// Reads its row of g2 from `buf`, overwrites it in place with the output.
__global__ void dm_horiz(float* __restrict__ buf) {
    __shared__ __align__(16) float row_g2[W];
    int row = blockIdx.x;        // 0 .. B*H-1
    int j = threadIdx.x;         // 0 .. W-1
    float* prow = buf + (size_t)row * W;
    row_g2[j] = prow[j];
    __syncthreads();

    float fj = (float)j;
    float best = 3.4e38f;
    #pragma unroll
    for (int jp = 0; jp < W; jp += 4) {
        // wave-uniform address -> LDS broadcast, conflict-free
        float4 v = *reinterpret_cast<const float4*>(&row_g2[jp]);
        float d0 = fj - (float)jp;
        float d1 = d0 - 1.0f;
        float d2 = d0 - 2.0f;
        float d3 = d0 - 3.0f;
        best = fminf(best, fmaf(d0, d0, v.x));
        best = fminf(best, fmaf(d1, d1, v.y));
        best = fminf(best, fmaf(d2, d2, v.z));
        best = fminf(best, fmaf(d3, d3, v.w));
    }

    float dist = sqrtf(best) * 0.1f;
    // sigmoid(-dist) * 2 = 2 / (1 + exp(dist))
    prow[j] = 2.0f / (1.0f + expf(dist));
}

extern "C" void kernel_launch(void* const* d_in, const int* in_sizes, int n_in,
                              void* d_out, int out_size, void* d_ws, size_t ws_size,
                              hipStream_t stream) {
    const float* mask = (const float*)d_in[0];
    float* out = (float*)d_out;

    dm_vert<<<(B * W + 255) / 256, 256, 0, stream>>>(mask, out);
    dm_horiz<<<B * H, W, 0, stream>>>(out);
}

// Round 2
// 14.611 us; speedup vs baseline: 2.0172x; 2.0172x over previous
//
#include <hip/hip_runtime.h>
#include <math.h>

namespace {
constexpr int B = 8, H = 192, W = 192;
constexpr float BIGF = 73728.0f;   // H*H + W*W sentinel (matches reference)
constexpr int WQ = 12;             // number of 16-row chunks per image (H/16)
constexpr int RPB = 4;             // rows per block in dm_rows
constexpr int R = 16;              // horizontal window radius (exact early-out)
}

// Kernel 1: pack fg = (mask > 0.5) into bit chunks.
// bits[(b*WQ + wq)*W + j] bit k  <=>  mask[b, wq*16 + k, j] > 0.5
// Grid: B*WQ blocks x W threads. All loads coalesced (192 consecutive floats
// per k-iteration), all 16 loads independent -> single vmcnt wait.
__global__ void __launch_bounds__(192) dm_bits(const float* __restrict__ mask,
                                               unsigned short* __restrict__ bits) {
    int b  = blockIdx.x / WQ;
    int wq = blockIdx.x - b * WQ;
    int j  = threadIdx.x;
    const float* base = mask + ((size_t)b * H + wq * 16) * W + j;
    unsigned int v = 0;
    #pragma unroll
    for (int k = 0; k < 16; ++k) {
        float m = base[(size_t)k * W];
        v |= (m > 0.5f ? 1u : 0u) << k;
    }
    bits[(b * WQ + wq) * W + j] = (unsigned short)v;
}

// Kernel 2: per (b, row-quad) block. Thread j reconstructs column j's 192-bit
// fg occupancy (3 x u64), gets nearest fg above/below each row i via clz/ffs
// (O(1), exact sentinel semantics), then does the exact horizontal EDT with a
// +/-16 window and a provable early-out (full scan fallback kept for exactness).
__global__ void __launch_bounds__(192) dm_rows(const unsigned short* __restrict__ bits,
                                               float* __restrict__ out) {
    __shared__ float g2p[RPB][W + 2 * R];  // padded row of squared vert. dists
    int bi = blockIdx.x;
    int b  = bi / (H / RPB);
    int i0 = (bi - b * (H / RPB)) * RPB;
    int j  = threadIdx.x;

    // Load the 12 u16 chunks of column j (coalesced: consecutive j -> consecutive u16)
    const unsigned short* cb = bits + b * WQ * W + j;
    unsigned long long lo = 0, mid = 0, hi = 0;
    #pragma unroll
    for (int wq = 0; wq < 4; ++wq) lo  |= (unsigned long long)cb[(size_t)wq * W]       << (16 * wq);
    #pragma unroll
    for (int wq = 0; wq < 4; ++wq) mid |= (unsigned long long)cb[(size_t)(4 + wq) * W] << (16 * wq);
    #pragma unroll
    for (int wq = 0; wq < 4; ++wq) hi  |= (unsigned long long)cb[(size_t)(8 + wq) * W] << (16 * wq);

    #pragma unroll
    for (int rr = 0; rr < RPB; ++rr) {
        int i = i0 + rr;
        int w = i >> 6;        // uniform across block
        int r = i & 63;        // uniform
        unsigned long long mle = (2ULL << r) - 1ULL;        // bits [0..r]
        unsigned long long mge = ~((1ULL << r) - 1ULL);     // bits [r..63]

        // words masked to rows <= i (for nearest-above = highest set bit)
        unsigned long long a0 = (w == 0) ? (lo  & mle) : lo;
        unsigned long long a1 = (w == 0) ? 0ULL : ((w == 1) ? (mid & mle) : mid);
        unsigned long long a2 = (w == 2) ? (hi  & mle) : 0ULL;
        // words masked to rows >= i (for nearest-below = lowest set bit)
        unsigned long long c0 = (w == 0) ? (lo  & mge) : 0ULL;
        unsigned long long c1 = (w == 1) ? (mid & mge) : ((w == 0) ? mid : 0ULL);
        unsigned long long c2 = (w == 2) ? (hi  & mge) : hi;

        int h2 = 191 - __clzll((long long)a2);
        int h1 = 127 - __clzll((long long)a1);
        int h0 = 63  - __clzll((long long)a0);
        int hidx = a2 ? h2 : (a1 ? h1 : (a0 ? h0 : -1));

        int lidx = c0 ? (__ffsll((unsigned long long)c0) - 1)
                 : (c1 ? (63 + __ffsll((unsigned long long)c1))
                 : (c2 ? (127 + __ffsll((unsigned long long)c2)) : -1));

        float fi   = (float)i;
        float up   = (hidx >= 0) ? (fi - (float)hidx) : (fi + BIGF);  // last = -BIG case
        float down = (lidx >= 0) ? ((float)lidx - fi) : (BIGF - fi);  // nxt  =  BIG case
        float d = fminf(fminf(up, down), BIGF);
        g2p[rr][R + j] = d * d;
        if (j < R)      g2p[rr][j] = 1e30f;           // left pad
        if (j >= W - R) g2p[rr][j + 2 * R] = 1e30f;   // right pad
    }
    __syncthreads();

    float fj = (float)j;
    #pragma unroll
    for (int rr = 0; rr < RPB; ++rr) {
        const float* row = &g2p[rr][R + j];
        float best = row[0];
        #pragma unroll
        for (int dj = 1; dj <= R; ++dj) {
            float c = (float)(dj * dj);
            best = fminf(best, row[dj]  + c);
            best = fminf(best, row[-dj] + c);
        }
        // Exact early-out: any |j-j'| > R contributes >= (R+1)^2 = 289 > 256.
        if (best > (float)(R * R)) {
            for (int jp = 0; jp < W; ++jp) {
                float diff = fj - (float)jp;
                best = fminf(best, fmaf(diff, diff, g2p[rr][R + jp]));
            }
        }
        float dist = sqrtf(best) * 0.1f;
        // sigmoid(-dist) * 2 == 2 / (1 + exp(dist))
        out[((size_t)b * H + (i0 + rr)) * W + j] = 2.0f / (1.0f + expf(dist));
    }
}

extern "C" void kernel_launch(void* const* d_in, const int* in_sizes, int n_in,
                              void* d_out, int out_size, void* d_ws, size_t ws_size,
                              hipStream_t stream) {
    const float* mask = (const float*)d_in[0];
    float* out = (float*)d_out;
    unsigned short* bits = (unsigned short*)d_ws;   // 8*12*192*2 = 36,864 B

    dm_bits<<<B * WQ, W, 0, stream>>>(mask, bits);
    dm_rows<<<B * (H / RPB), W, 0, stream>>>(bits, out);
}

// Round 3
// 11.056 us; speedup vs baseline: 2.6656x; 1.3215x over previous
//
#include <hip/hip_runtime.h>
#include <math.h>

namespace {
constexpr int B = 8, H = 192, W = 192;
constexpr float BIGF = 73728.0f;   // H*H + W*W sentinel (matches reference)
constexpr int BAND = 16;           // output rows per block
constexpr int RWIN = 4;            // primary horizontal window radius
constexpr int RESC = 16;           // escalation window radius == LDS pad
constexpr int NT   = 768;          // 12 waves
}

// One fused kernel. Grid: 8 images x 12 bands = 96 blocks.
// blockIdx & 7 = image  ->  all 12 blocks of an image land on one XCD
// (round-robin heuristic), so the image's mask stays in that XCD's L2
// across graph replays.
__global__ void __launch_bounds__(NT) dm_fused(const float* __restrict__ mask,
                                               float* __restrict__ out) {
    __shared__ unsigned long long colbits[3][W];       // 4.6 KB
    __shared__ float g2p[4][W + 2 * RESC];             // 3.5 KB, padded rows

    const int b    = blockIdx.x & 7;
    const int band = blockIdx.x >> 3;
    const int i0   = band * BAND;
    const int tid  = threadIdx.x;

    // ---- Phase 1: column fg bitmasks (3 u64 words / column) -------------
    // 576 threads: task (w = word 0..2, jj = column). Per k-iteration the
    // wave's 64 lanes read 64 consecutive floats of one row -> coalesced.
    // All 64 loads independent -> deep pipelining; L2-hit in steady state.
    if (tid < 3 * W) {
        const int w  = tid / W;            // uniform per wave
        const int jj = tid - w * W;
        const float* p = mask + ((size_t)b * H + w * 64) * W + jj;
        unsigned long long v = 0;
        #pragma unroll
        for (int k = 0; k < 64; ++k) {
            v |= (unsigned long long)(p[(size_t)k * W] > 0.5f ? 1u : 0u) << k;
        }
        colbits[w][jj] = v;
    } else {
        // waves 9..11: fill the constant LDS pads once (never rewritten)
        int t = tid - 3 * W;               // 0..191
        if (t < 4 * 2 * RESC) {            // 128 pad slots
            int r = t >> 5;                // row 0..3
            int c = t & 31;                // 0..31
            int idx = (c < RESC) ? c : (W + RESC + (c - RESC));
            g2p[r][idx] = 1e30f;
        }
    }
    __syncthreads();

    // ---- Phase 2: 4 sweeps x 4 rows ------------------------------------
    const int j  = tid % W;                // consecutive within each wave
    const int ig = tid / W;                // 0..3 (uniform per wave)
    const unsigned long long lo  = colbits[0][j];
    const unsigned long long mid = colbits[1][j];
    const unsigned long long hi  = colbits[2][j];
    const float fj = (float)j;

    #pragma unroll
    for (int s = 0; s < BAND / 4; ++s) {
        const int i = i0 + s * 4 + ig;

        // vertical nearest-fg above/below via clz/ffs — exact sentinel
        // algebra, bit-identical to the reference cummax formulation
        // (verified absmax 0.0 in round 2).
        const int wdi = i >> 6, r = i & 63;
        const unsigned long long mle = (2ULL << r) - 1ULL;   // bits [0..r]
        const unsigned long long mge = ~((1ULL << r) - 1ULL);// bits [r..63]
        unsigned long long a0 = (wdi == 0) ? (lo & mle) : lo;
        unsigned long long a1 = (wdi == 0) ? 0ULL : ((wdi == 1) ? (mid & mle) : mid);
        unsigned long long a2 = (wdi == 2) ? (hi & mle) : 0ULL;
        unsigned long long c0 = (wdi == 0) ? (lo & mge) : 0ULL;
        unsigned long long c1 = (wdi == 1) ? (mid & mge) : ((wdi == 0) ? mid : 0ULL);
        unsigned long long c2 = (wdi == 2) ? (hi & mge) : hi;

        int hidx = a2 ? (191 - __clzll((long long)a2))
                 : (a1 ? (127 - __clzll((long long)a1))
                 : (a0 ? (63 - __clzll((long long)a0)) : -1));
        int lidx = c0 ? (__ffsll((unsigned long long)c0) - 1)
                 : (c1 ? (63 + __ffsll((unsigned long long)c1))
                 : (c2 ? (127 + __ffsll((unsigned long long)c2)) : -1));

        const float fi   = (float)i;
        const float up   = (hidx >= 0) ? (fi - (float)hidx) : (fi + BIGF);
        const float down = (lidx >= 0) ? ((float)lidx - fi) : (BIGF - fi);
        const float d = fminf(fminf(up, down), BIGF);
        g2p[ig][RESC + j] = d * d;
        __syncthreads();

        // horizontal exact EDT: ±4 window, provable early-out escalation.
        // Beyond-window taps contribute >= (RWIN+1)^2 = 25 > 16, so
        // best <= 16 certifies exactness; likewise 256 for the ±16 stage;
        // full-row fallback keeps exactness on any input.
        const float* rowp = &g2p[ig][RESC + j];
        float best = rowp[0];
        #pragma unroll
        for (int dj = 1; dj <= RWIN; ++dj) {
            const float c = (float)(dj * dj);
            best = fminf(best, rowp[dj]  + c);
            best = fminf(best, rowp[-dj] + c);
        }
        if (__any(best > (float)(RWIN * RWIN))) {
            #pragma unroll
            for (int dj = RWIN + 1; dj <= RESC; ++dj) {
                const float c = (float)(dj * dj);
                best = fminf(best, rowp[dj]  + c);
                best = fminf(best, rowp[-dj] + c);
            }
            if (__any(best > (float)(RESC * RESC))) {
                for (int jp = 0; jp < W; ++jp) {
                    const float diff = fj - (float)jp;
                    best = fminf(best, fmaf(diff, diff, g2p[ig][RESC + jp]));
                }
            }
        }

        const float dist = sqrtf(best) * 0.1f;
        // sigmoid(-dist) * 2 == 2 / (1 + exp(dist))
        out[((size_t)b * H + i) * W + j] = __fdividef(2.0f, 1.0f + __expf(dist));
        __syncthreads();   // protect g2p row before next sweep overwrites it
    }
}

extern "C" void kernel_launch(void* const* d_in, const int* in_sizes, int n_in,
                              void* d_out, int out_size, void* d_ws, size_t ws_size,
                              hipStream_t stream) {
    const float* mask = (const float*)d_in[0];
    float* out = (float*)d_out;
    dm_fused<<<B * (H / BAND), NT, 0, stream>>>(mask, out);
}

// Round 4
// 10.527 us; speedup vs baseline: 2.7998x; 1.0503x over previous
//
#include <hip/hip_runtime.h>
#include <math.h>

namespace {
constexpr int B = 8, H = 192, W = 192;
constexpr float BIGF = 73728.0f;   // H*H + W*W sentinel (matches reference)
constexpr int BAND = 16;           // output rows per block
constexpr int RWIN = 4;            // primary horizontal window radius
constexpr int RESC = 16;           // escalation window radius == LDS pad
constexpr int NT   = 768;          // 12 waves
constexpr int WP   = W + 2 * RESC; // padded row length (224)
}

// One fused kernel, 2 barriers total. Grid: 8 images x 12 bands = 96 blocks.
// blockIdx & 7 = image -> all 12 blocks of an image land on one XCD
// (round-robin heuristic) for L2 locality of the mask.
__global__ void __launch_bounds__(NT) dm_fused(const float* __restrict__ mask,
                                               float* __restrict__ out) {
    __shared__ unsigned long long colbits[3][W];   // 4.6 KB
    __shared__ float g2p[BAND][WP];                // 14.3 KB, padded rows

    const int b    = blockIdx.x & 7;
    const int band = blockIdx.x >> 3;
    const int i0   = band * BAND;
    const int tid  = threadIdx.x;

    // ---- Phase 1: column fg bitmasks (3 u64 words / column) -------------
    // Threads 0..575: word w of column jj. Per k the wave's lanes read
    // consecutive floats -> coalesced. Four independent 16-bit accumulators
    // keep the OR chain depth at ~16 instead of 64.
    if (tid < 3 * W) {
        const int w  = tid / W;            // wave-uniform
        const int jj = tid - w * W;
        const float* p = mask + ((size_t)b * H + w * 64) * W + jj;
        unsigned long long v0 = 0, v1 = 0, v2 = 0, v3 = 0;
        #pragma unroll
        for (int k = 0; k < 16; ++k) {
            v0 |= (unsigned long long)(p[(size_t)k * W]        > 0.5f) << k;
            v1 |= (unsigned long long)(p[(size_t)(k + 16) * W] > 0.5f) << k;
            v2 |= (unsigned long long)(p[(size_t)(k + 32) * W] > 0.5f) << k;
            v3 |= (unsigned long long)(p[(size_t)(k + 48) * W] > 0.5f) << k;
        }
        colbits[w][jj] = v0 | (v1 << 16) | (v2 << 32) | (v3 << 48);
    } else {
        // threads 576..767: fill the constant LDS pads (written once only)
        const int t = tid - 3 * W;         // 0..191
        for (int s = t; s < BAND * 2 * RESC; s += 192) {
            const int r = s >> 5;          // row 0..15
            const int c = s & 31;          // 0..31
            const int idx = (c < RESC) ? c : (W + RESC + (c - RESC));
            g2p[r][idx] = 1e30f;
        }
    }
    __syncthreads();

    // ---- Phase 2: vertical distances for all 16 rows ---------------------
    const int j  = tid % W;                // consecutive within each wave
    const int ig = tid / W;                // 0..3, wave-uniform
    const unsigned long long lo  = colbits[0][j];
    const unsigned long long mid = colbits[1][j];
    const unsigned long long hi  = colbits[2][j];

    #pragma unroll
    for (int rr = 0; rr < BAND / 4; ++rr) {
        const int i = i0 + rr * 4 + ig;

        // nearest fg above/below via clz/ffs — exact sentinel algebra,
        // bit-identical to the reference cummax formulation (absmax 0.0
        // in rounds 2 and 3).
        const int wdi = i >> 6, r = i & 63;
        const unsigned long long mle = (2ULL << r) - 1ULL;    // bits [0..r]
        const unsigned long long mge = ~((1ULL << r) - 1ULL); // bits [r..63]
        unsigned long long a0 = (wdi == 0) ? (lo & mle) : lo;
        unsigned long long a1 = (wdi == 0) ? 0ULL : ((wdi == 1) ? (mid & mle) : mid);
        unsigned long long a2 = (wdi == 2) ? (hi & mle) : 0ULL;
        unsigned long long c0 = (wdi == 0) ? (lo & mge) : 0ULL;
        unsigned long long c1 = (wdi == 1) ? (mid & mge) : ((wdi == 0) ? mid : 0ULL);
        unsigned long long c2 = (wdi == 2) ? (hi & mge) : hi;

        int hidx = a2 ? (191 - __clzll((long long)a2))
                 : (a1 ? (127 - __clzll((long long)a1))
                 : (a0 ? (63 - __clzll((long long)a0)) : -1));
        int lidx = c0 ? (__ffsll((unsigned long long)c0) - 1)
                 : (c1 ? (63 + __ffsll((unsigned long long)c1))
                 : (c2 ? (127 + __ffsll((unsigned long long)c2)) : -1));

        const float fi   = (float)i;
        const float up   = (hidx >= 0) ? (fi - (float)hidx) : (fi + BIGF);
        const float down = (lidx >= 0) ? ((float)lidx - fi) : (BIGF - fi);
        const float d = fminf(fminf(up, down), BIGF);
        g2p[rr * 4 + ig][RESC + j] = d * d;
    }
    __syncthreads();

    // ---- Phase 3: horizontal exact EDT + epilogue, no further barriers ---
    const float fj = (float)j;
    #pragma unroll
    for (int rr = 0; rr < BAND / 4; ++rr) {
        const int row = rr * 4 + ig;
        const float* rowp = &g2p[row][RESC + j];
        float best = rowp[0];
        #pragma unroll
        for (int dj = 1; dj <= RWIN; ++dj) {
            const float c = (float)(dj * dj);
            best = fminf(best, rowp[dj]  + c);
            best = fminf(best, rowp[-dj] + c);
        }
        // Exact escalation: beyond-window taps contribute >= (RWIN+1)^2 = 25,
        // so best <= 16 certifies exactness; likewise 256 for the ±16 stage;
        // full-row fallback keeps exactness on any input.
        if (__any(best > (float)(RWIN * RWIN))) {
            #pragma unroll
            for (int dj = RWIN + 1; dj <= RESC; ++dj) {
                const float c = (float)(dj * dj);
                best = fminf(best, rowp[dj]  + c);
                best = fminf(best, rowp[-dj] + c);
            }
            if (__any(best > (float)(RESC * RESC))) {
                for (int jp = 0; jp < W; ++jp) {
                    const float diff = fj - (float)jp;
                    best = fminf(best, fmaf(diff, diff, g2p[row][RESC + jp]));
                }
            }
        }

        const float dist = sqrtf(best) * 0.1f;
        // sigmoid(-dist) * 2 == 2 / (1 + exp(dist))
        out[((size_t)b * H + (i0 + row)) * W + j] = __fdividef(2.0f, 1.0f + __expf(dist));
    }
}

extern "C" void kernel_launch(void* const* d_in, const int* in_sizes, int n_in,
                              void* d_out, int out_size, void* d_ws, size_t ws_size,
                              hipStream_t stream) {
    const float* mask = (const float*)d_in[0];
    float* out = (float*)d_out;
    dm_fused<<<B * (H / BAND), NT, 0, stream>>>(mask, out);
}

// Round 5
// 10.314 us; speedup vs baseline: 2.8575x; 1.0206x over previous
//
#include <hip/hip_runtime.h>
#include <math.h>

namespace {
constexpr int B = 8, H = 192, W = 192;
constexpr float BIGF = 73728.0f;   // H*H + W*W sentinel (matches reference)
constexpr int BAND = 16;           // output rows per block
constexpr int RWIN = 4;            // primary horizontal window radius
constexpr int RESC = 16;           // escalation window radius == LDS pad
constexpr int NT   = 768;          // 12 waves
constexpr int WP   = W + 2 * RESC; // padded row length (224)
}

// One fused kernel, 2 barriers. Grid: 8 images x 12 bands = 96 blocks.
// blockIdx & 7 = image -> all 12 blocks of an image share one XCD's L2.
__global__ void __launch_bounds__(NT) dm_fused(const float* __restrict__ mask,
                                               float* __restrict__ out) {
    __shared__ unsigned long long chunk64[12][48];  // 4.6 KB: u16 fg-bits, 4 cols/entry
    __shared__ float g2p[BAND][WP];                 // 14.3 KB, padded rows

    const int b    = blockIdx.x & 7;
    const int band = blockIdx.x >> 3;
    const int i0   = band * BAND;
    const int tid  = threadIdx.x;

    // ---- Phase 1: fg bitmask chunks via float4 loads ---------------------
    // Task (wq = 16-row chunk 0..11, g = 4-column group 0..47): 16 dwordx4
    // loads (1 KB/wave-instruction), 4 independent 16-deep OR chains, one
    // ds_write_b64. 144 vmem instructions per block (was 576 scalar).
    if (tid < 576) {
        const int wq = tid / 48;           // row chunk
        const int g  = tid - wq * 48;      // column group
        const float4* p = (const float4*)(mask + ((size_t)b * H + wq * 16) * W) + g;
        unsigned int v0 = 0, v1 = 0, v2 = 0, v3 = 0;
        #pragma unroll
        for (int k = 0; k < 16; ++k) {
            const float4 m = p[(size_t)k * (W / 4)];
            v0 |= (m.x > 0.5f ? 1u : 0u) << k;
            v1 |= (m.y > 0.5f ? 1u : 0u) << k;
            v2 |= (m.z > 0.5f ? 1u : 0u) << k;
            v3 |= (m.w > 0.5f ? 1u : 0u) << k;
        }
        // little-endian u16 pack: ushort index wq*192 + 4g + c == column 4g+c
        chunk64[wq][g] = (unsigned long long)v0
                       | ((unsigned long long)v1 << 16)
                       | ((unsigned long long)v2 << 32)
                       | ((unsigned long long)v3 << 48);
    } else {
        // threads 576..767: fill the constant LDS pads (written once only)
        const int t = tid - 576;           // 0..191
        for (int s = t; s < BAND * 2 * RESC; s += 192) {
            const int r = s >> 5;          // row 0..15
            const int c = s & 31;          // 0..31
            const int idx = (c < RESC) ? c : (W + RESC + (c - RESC));
            g2p[r][idx] = 1e30f;
        }
    }
    __syncthreads();

    // ---- Phase 2: vertical distances for all 16 rows ---------------------
    {
        const int j  = tid % W;            // column owner
        const int ig = tid / W;            // 0..3, wave-uniform
        const unsigned short* c16 = (const unsigned short*)chunk64;
        unsigned long long lo = 0, mid = 0, hi = 0;
        #pragma unroll
        for (int wq = 0; wq < 4; ++wq) lo  |= (unsigned long long)c16[wq * 192 + j]       << (16 * wq);
        #pragma unroll
        for (int wq = 0; wq < 4; ++wq) mid |= (unsigned long long)c16[(4 + wq) * 192 + j] << (16 * wq);
        #pragma unroll
        for (int wq = 0; wq < 4; ++wq) hi  |= (unsigned long long)c16[(8 + wq) * 192 + j] << (16 * wq);

        #pragma unroll
        for (int rr = 0; rr < BAND / 4; ++rr) {
            const int i = i0 + rr * 4 + ig;
            // nearest fg above/below via clz/ffs — exact sentinel algebra,
            // bit-identical to the reference cummax path (absmax 0.0, R2-R4).
            const int wdi = i >> 6, r = i & 63;
            const unsigned long long mle = (2ULL << r) - 1ULL;    // bits [0..r]
            const unsigned long long mge = ~((1ULL << r) - 1ULL); // bits [r..63]
            unsigned long long a0 = (wdi == 0) ? (lo & mle) : lo;
            unsigned long long a1 = (wdi == 0) ? 0ULL : ((wdi == 1) ? (mid & mle) : mid);
            unsigned long long a2 = (wdi == 2) ? (hi & mle) : 0ULL;
            unsigned long long c0 = (wdi == 0) ? (lo & mge) : 0ULL;
            unsigned long long c1 = (wdi == 1) ? (mid & mge) : ((wdi == 0) ? mid : 0ULL);
            unsigned long long c2 = (wdi == 2) ? (hi & mge) : hi;

            int hidx = a2 ? (191 - __clzll((long long)a2))
                     : (a1 ? (127 - __clzll((long long)a1))
                     : (a0 ? (63 - __clzll((long long)a0)) : -1));
            int lidx = c0 ? (__ffsll((unsigned long long)c0) - 1)
                     : (c1 ? (63 + __ffsll((unsigned long long)c1))
                     : (c2 ? (127 + __ffsll((unsigned long long)c2)) : -1));

            const float fi   = (float)i;
            const float up   = (hidx >= 0) ? (fi - (float)hidx) : (fi + BIGF);
            const float down = (lidx >= 0) ? ((float)lidx - fi) : (BIGF - fi);
            const float d = fminf(fminf(up, down), BIGF);
            g2p[rr * 4 + ig][RESC + j] = d * d;
        }
    }
    __syncthreads();

    // ---- Phase 3: horizontal exact EDT + epilogue, vectorized ------------
    // Thread (rloc = row 0..15, g = 4-column group 0..47): the ±4 windows of
    // columns 4g..4g+3 share 12 contiguous taps -> 3 ds_read_b128, then one
    // global_store_dwordx4. Tap values/ops identical to R4 (exactness kept).
    {
        const int rloc  = tid / 48;
        const int g     = tid - rloc * 48;
        const int jbase = 4 * g;
        const float* rowbase = &g2p[rloc][RESC + jbase];

        float t[12];
        const float4 w0 = *(const float4*)(rowbase - 4);
        const float4 w1 = *(const float4*)(rowbase);
        const float4 w2 = *(const float4*)(rowbase + 4);
        t[0] = w0.x; t[1] = w0.y; t[2]  = w0.z; t[3]  = w0.w;
        t[4] = w1.x; t[5] = w1.y; t[6]  = w1.z; t[7]  = w1.w;
        t[8] = w2.x; t[9] = w2.y; t[10] = w2.z; t[11] = w2.w;

        float best[4];
        #pragma unroll
        for (int c = 0; c < 4; ++c) {
            float bst = t[c + 4];
            #pragma unroll
            for (int dj = 1; dj <= RWIN; ++dj) {
                const float cc = (float)(dj * dj);
                bst = fminf(bst, t[c + 4 + dj] + cc);
                bst = fminf(bst, t[c + 4 - dj] + cc);
            }
            best[c] = bst;
        }

        // Exact escalation: taps beyond ±4 contribute >= 25, so best <= 16
        // certifies exactness; adding taps when best <= 16 can never change
        // the min, so escalating all 4 columns together stays exact.
        float mx = fmaxf(fmaxf(best[0], best[1]), fmaxf(best[2], best[3]));
        if (__any(mx > (float)(RWIN * RWIN))) {
            #pragma unroll
            for (int c = 0; c < 4; ++c) {
                #pragma unroll
                for (int dj = RWIN + 1; dj <= RESC; ++dj) {
                    const float cc = (float)(dj * dj);
                    best[c] = fminf(best[c], rowbase[c + dj] + cc);
                    best[c] = fminf(best[c], rowbase[c - dj] + cc);
                }
            }
            mx = fmaxf(fmaxf(best[0], best[1]), fmaxf(best[2], best[3]));
            if (__any(mx > (float)(RESC * RESC))) {
                for (int jp = 0; jp < W; ++jp) {
                    const float gv = g2p[rloc][RESC + jp];
                    #pragma unroll
                    for (int c = 0; c < 4; ++c) {
                        const float diff = (float)(jbase + c) - (float)jp;
                        best[c] = fminf(best[c], fmaf(diff, diff, gv));
                    }
                }
            }
        }

        float4 o;
        {
            const float d0 = sqrtf(best[0]) * 0.1f;
            const float d1 = sqrtf(best[1]) * 0.1f;
            const float d2 = sqrtf(best[2]) * 0.1f;
            const float d3 = sqrtf(best[3]) * 0.1f;
            // sigmoid(-d) * 2 == 2 / (1 + exp(d))
            o.x = __fdividef(2.0f, 1.0f + __expf(d0));
            o.y = __fdividef(2.0f, 1.0f + __expf(d1));
            o.z = __fdividef(2.0f, 1.0f + __expf(d2));
            o.w = __fdividef(2.0f, 1.0f + __expf(d3));
        }
        *(float4*)(out + ((size_t)b * H + (i0 + rloc)) * W + jbase) = o;
    }
}

extern "C" void kernel_launch(void* const* d_in, const int* in_sizes, int n_in,
                              void* d_out, int out_size, void* d_ws, size_t ws_size,
                              hipStream_t stream) {
    const float* mask = (const float*)d_in[0];
    float* out = (float*)d_out;
    dm_fused<<<B * (H / BAND), NT, 0, stream>>>(mask, out);
}